// Round 1
// baseline (2575.576 us; speedup 1.0000x reference)
//
#include <hip/hip_runtime.h>
#include <math.h>

#define D_DIM 1024
#define S_DIM 4096
#define B_DIM 4
#define CHUNK 64
#define NC (S_DIM / CHUNK)
#define M_DIM (B_DIM * S_DIM)   // 16384 rows

// ---------------------------------------------------------------------------
// fp32 tiled GEMM: C[M,N] = A[M,K] @ W[K,N] + bias[N] (+ res[M,N])
// BM=BN=128, BK=16, 256 threads, 8x8 per thread.
// No fp32 MFMA on CDNA4 -> vector FMA; LDS-BW-limited ~65% of 157 TF.
// ---------------------------------------------------------------------------
constexpr int BM = 128, BN = 128, BK = 16, TM = 8, TN = 8;
constexpr int ASTRIDE = BM + 4;   // +4 keeps 16B alignment (528B rows) & breaks bank stride

template <bool HAS_RES>
__global__ __launch_bounds__(256) void gemm128(const float* __restrict__ A,
                                               const float* __restrict__ W,
                                               const float* __restrict__ bias,
                                               const float* __restrict__ res,
                                               float* __restrict__ C,
                                               int M, int N, int K) {
  __shared__ float As[BK * ASTRIDE];   // transposed: As[k][m]
  __shared__ float Ws[BK * BN];        // Ws[k][n]

  const int tid = threadIdx.x;
  const int bm = blockIdx.y * BM;
  const int bn = blockIdx.x * BN;
  const int tx = tid & 15;   // n-tile index
  const int ty = tid >> 4;   // m-tile index

  float acc[TM][TN];
#pragma unroll
  for (int i = 0; i < TM; i++)
#pragma unroll
    for (int j = 0; j < TN; j++) acc[i][j] = 0.f;

  for (int k0 = 0; k0 < K; k0 += BK) {
    // A tile 128x16 -> LDS transposed. 512 float4 / 256 threads = 2 each.
#pragma unroll
    for (int l = 0; l < 2; l++) {
      int idx = tid + l * 256;
      int row = idx >> 2;
      int kv = (idx & 3) * 4;
      const float4 av = *(const float4*)(A + (size_t)(bm + row) * K + k0 + kv);
      As[(kv + 0) * ASTRIDE + row] = av.x;
      As[(kv + 1) * ASTRIDE + row] = av.y;
      As[(kv + 2) * ASTRIDE + row] = av.z;
      As[(kv + 3) * ASTRIDE + row] = av.w;
    }
    // W tile 16x128, contiguous float4.
#pragma unroll
    for (int l = 0; l < 2; l++) {
      int idx = tid + l * 256;
      int kr = idx >> 5;
      int nv = (idx & 31) * 4;
      *(float4*)(Ws + kr * BN + nv) =
          *(const float4*)(W + (size_t)(k0 + kr) * N + bn + nv);
    }
    __syncthreads();

#pragma unroll
    for (int k = 0; k < BK; k++) {
      float a[TM], b[TN];
#pragma unroll
      for (int i = 0; i < 2; i++)
        *(float4*)(a + 4 * i) = *(const float4*)(As + k * ASTRIDE + ty * TM + 4 * i);
#pragma unroll
      for (int j = 0; j < 2; j++)
        *(float4*)(b + 4 * j) = *(const float4*)(Ws + k * BN + tx * TN + 4 * j);
#pragma unroll
      for (int i = 0; i < TM; i++)
#pragma unroll
        for (int j = 0; j < TN; j++) acc[i][j] = fmaf(a[i], b[j], acc[i][j]);
    }
    __syncthreads();
  }

#pragma unroll
  for (int i = 0; i < TM; i++) {
    int m = bm + ty * TM + i;
#pragma unroll
    for (int j = 0; j < TN; j += 4) {
      int n = bn + tx * TN + j;
      float4 v;
      v.x = acc[i][j + 0] + bias[n + 0];
      v.y = acc[i][j + 1] + bias[n + 1];
      v.z = acc[i][j + 2] + bias[n + 2];
      v.w = acc[i][j + 3] + bias[n + 3];
      if (HAS_RES) {
        const float4 r = *(const float4*)(res + (size_t)m * N + n);
        v.x += r.x; v.y += r.y; v.z += r.z; v.w += r.w;
      }
      *(float4*)(C + (size_t)m * N + n) = v;
    }
  }
}

// ---------------------------------------------------------------------------
// Fused phasor scan: trig computed inline (kc/ks/qc/qs never materialized),
// cumsum over the 64 rows of each chunk, retrieved = (mr*qc+mi*qs)/sqrt(S).
// One thread owns 2 columns of one (b, chunk); rows loop serially (coalesced
// across the wave at every row).
// ---------------------------------------------------------------------------
__global__ __launch_bounds__(256) void phasor_scan(const float* __restrict__ value,
                                                   const float* __restrict__ kp,
                                                   const float* __restrict__ qp,
                                                   float* __restrict__ ret) {
  const int half = blockIdx.x;    // 0..1
  const int chunk = blockIdx.y;   // 0..NC-1
  const int b = blockIdx.z;       // 0..B-1
  const int col = half * 512 + threadIdx.x * 2;
  size_t base = ((size_t)(b * S_DIM + chunk * CHUNK)) * D_DIM + col;
  float2 mr = {0.f, 0.f}, mi = {0.f, 0.f};
  const float inv = 0.015625f;  // 1/sqrt(4096)
  for (int s = 0; s < CHUNK; s++) {
    size_t off = base + (size_t)s * D_DIM;
    float2 v = *(const float2*)(value + off);
    float2 k2 = *(const float2*)(kp + off);
    float2 q2 = *(const float2*)(qp + off);
    float sk, ck, sq, cq;
    sincosf(k2.x, &sk, &ck);
    mr.x = fmaf(v.x, ck, mr.x);
    mi.x = fmaf(v.x, sk, mi.x);
    sincosf(k2.y, &sk, &ck);
    mr.y = fmaf(v.y, ck, mr.y);
    mi.y = fmaf(v.y, sk, mi.y);
    float2 r;
    sincosf(q2.x, &sq, &cq);
    r.x = (mr.x * cq + mi.x * sq) * inv;
    sincosf(q2.y, &sq, &cq);
    r.y = (mr.y * cq + mi.y * sq) * inv;
    *(float2*)(ret + off) = r;
  }
}

// ---------------------------------------------------------------------------
// LayerNorm over D=1024 per row; one 256-thread block per row, float4/thread.
// ---------------------------------------------------------------------------
__global__ __launch_bounds__(256) void layernorm_k(const float* __restrict__ ret,
                                                   const float* __restrict__ g,
                                                   const float* __restrict__ bln,
                                                   float* __restrict__ out) {
  const int row = blockIdx.x;
  const float* r = ret + (size_t)row * D_DIM;
  const float4 v = *(const float4*)(r + threadIdx.x * 4);
  float s = v.x + v.y + v.z + v.w;
  float ss = v.x * v.x + v.y * v.y + v.z * v.z + v.w * v.w;
#pragma unroll
  for (int o = 32; o > 0; o >>= 1) {
    s += __shfl_down(s, o);
    ss += __shfl_down(ss, o);
  }
  __shared__ float red[8];
  const int wid = threadIdx.x >> 6;
  if ((threadIdx.x & 63) == 0) {
    red[wid] = s;
    red[4 + wid] = ss;
  }
  __syncthreads();
  if (threadIdx.x == 0) {
    float ts = red[0] + red[1] + red[2] + red[3];
    float tss = red[4] + red[5] + red[6] + red[7];
    float mu = ts * (1.f / D_DIM);
    float var = tss * (1.f / D_DIM) - mu * mu;
    red[0] = mu;
    red[1] = 1.f / sqrtf(var + 1e-5f);
  }
  __syncthreads();
  const float mu = red[0], rs = red[1];
  const float4 gv = *(const float4*)(g + threadIdx.x * 4);
  const float4 bv = *(const float4*)(bln + threadIdx.x * 4);
  float4 o;
  o.x = (v.x - mu) * rs * gv.x + bv.x;
  o.y = (v.y - mu) * rs * gv.y + bv.y;
  o.z = (v.z - mu) * rs * gv.z + bv.z;
  o.w = (v.w - mu) * rs * gv.w + bv.w;
  *(float4*)(out + (size_t)row * D_DIM + threadIdx.x * 4) = o;
}

// ---------------------------------------------------------------------------
// Ortho loss: dot[b,i,j,d] = cos(kp_i,d)cos(kp_j,d)+sin..sin.. = cos(kp_i-kp_j)
// Block = (i, b); loops j, partial per block; deterministic 2-stage reduce.
// ---------------------------------------------------------------------------
__global__ __launch_bounds__(256) void ortho_partial(const float* __restrict__ kp,
                                                     const int* __restrict__ idx,
                                                     float* __restrict__ partial) {
  const int i = blockIdx.x;  // 0..31
  const int b = blockIdx.y;  // 0..3
  const int ri = idx[i];
  const float4 a = *(const float4*)(kp + ((size_t)b * S_DIM + ri) * D_DIM + threadIdx.x * 4);
  float sum = 0.f;
  for (int j = 0; j < 32; j++) {
    if (j == i) continue;
    const int rj = idx[j];
    const float4 c = *(const float4*)(kp + ((size_t)b * S_DIM + rj) * D_DIM + threadIdx.x * 4);
    float d0 = cosf(a.x - c.x);
    float d1 = cosf(a.y - c.y);
    float d2 = cosf(a.z - c.z);
    float d3 = cosf(a.w - c.w);
    sum += d0 * d0 + d1 * d1 + d2 * d2 + d3 * d3;
  }
#pragma unroll
  for (int o = 32; o > 0; o >>= 1) sum += __shfl_down(sum, o);
  __shared__ float red[4];
  if ((threadIdx.x & 63) == 0) red[threadIdx.x >> 6] = sum;
  __syncthreads();
  if (threadIdx.x == 0) partial[b * 32 + i] = red[0] + red[1] + red[2] + red[3];
}

__global__ void ortho_final(const float* __restrict__ partial, float* __restrict__ outp) {
  if (threadIdx.x == 0) {
    double s = 0.0;
    for (int t = 0; t < 128; t++) s += (double)partial[t];
    const double denom = (double)(32 * 31) * 1024.0 + 1e-6;
    outp[0] = (float)(s / denom);
  }
}

// ---------------------------------------------------------------------------
// Orchestration. 3 x 64MB ws buffers via liveness-aware ordering:
//   ws0: key  -> qphase        ws1: query -> value -> ln        ws2: kphase
//   retrieved lives in d_out, consumed by LN before final GEMM overwrites.
// ---------------------------------------------------------------------------
extern "C" void kernel_launch(void* const* d_in, const int* in_sizes, int n_in,
                              void* d_out, int out_size, void* d_ws, size_t ws_size,
                              hipStream_t stream) {
  const float* x = (const float*)d_in[0];
  const float* Wk = (const float*)d_in[1];
  const float* bk = (const float*)d_in[2];
  const float* Wv = (const float*)d_in[3];
  const float* bv = (const float*)d_in[4];
  const float* Wq = (const float*)d_in[5];
  const float* bq = (const float*)d_in[6];
  const float* Wkp = (const float*)d_in[7];
  const float* bkp = (const float*)d_in[8];
  const float* Wqp = (const float*)d_in[9];
  const float* bqp = (const float*)d_in[10];
  const float* ln_g = (const float*)d_in[11];
  const float* ln_b = (const float*)d_in[12];
  const float* Wo = (const float*)d_in[13];
  const float* bo = (const float*)d_in[14];
  const int* idx = (const int*)d_in[15];

  float* out = (float*)d_out;
  float* ortho_out = out + (size_t)M_DIM * D_DIM;

  const size_t NELEM = (size_t)M_DIM * D_DIM;
  float* ws0 = (float*)d_ws;          // key -> qphase
  float* ws1 = ws0 + NELEM;           // query -> value -> ln
  float* ws2 = ws1 + NELEM;           // kphase
  float* partial = ws2 + NELEM;       // 128 floats

  const dim3 gg(D_DIM / BN, M_DIM / BM);  // (8, 128)

  // 1. key = x@Wk + bk
  gemm128<false><<<gg, 256, 0, stream>>>(x, Wk, bk, nullptr, ws0, M_DIM, D_DIM, D_DIM);
  // 2. query = x@Wq + bq
  gemm128<false><<<gg, 256, 0, stream>>>(x, Wq, bq, nullptr, ws1, M_DIM, D_DIM, D_DIM);
  // 3. kphase = key@Wkp + bkp
  gemm128<false><<<gg, 256, 0, stream>>>(ws0, Wkp, bkp, nullptr, ws2, M_DIM, D_DIM, D_DIM);
  // 4. qphase = query@Wqp + bqp   (overwrites key)
  gemm128<false><<<gg, 256, 0, stream>>>(ws1, Wqp, bqp, nullptr, ws0, M_DIM, D_DIM, D_DIM);
  // 5. value = x@Wv + bv          (overwrites query)
  gemm128<false><<<gg, 256, 0, stream>>>(x, Wv, bv, nullptr, ws1, M_DIM, D_DIM, D_DIM);
  // 6. ortho from kphase
  ortho_partial<<<dim3(32, B_DIM), 256, 0, stream>>>(ws2, idx, partial);
  ortho_final<<<1, 64, 0, stream>>>(partial, ortho_out);
  // 7. fused trig + chunk cumsum + retrieve -> d_out
  phasor_scan<<<dim3(2, NC, B_DIM), 256, 0, stream>>>(ws1, ws2, ws0, out);
  // 8. LayerNorm -> ws1
  layernorm_k<<<M_DIM, 256, 0, stream>>>(out, ln_g, ln_b, ws1);
  // 9. out = x + ln@Wo + bo
  gemm128<true><<<gg, 256, 0, stream>>>(ws1, Wo, bo, x, out, M_DIM, D_DIM, D_DIM);
}

// Round 2
// 637.701 us; speedup vs baseline: 4.0388x; 4.0388x over previous
//
#include <hip/hip_runtime.h>
#include <math.h>

#define D_DIM 1024
#define S_DIM 4096
#define B_DIM 4
#define CHUNK 64
#define NC (S_DIM / CHUNK)
#define M_DIM (B_DIM * S_DIM)   // 16384 rows

typedef __bf16 bf16_t;
typedef __attribute__((ext_vector_type(8))) __bf16 bf16x8;
typedef __attribute__((ext_vector_type(4))) __bf16 bf16x4;
typedef __attribute__((ext_vector_type(4))) float f32x4;

// ---------------------------------------------------------------------------
// async 16B/lane global->LDS. LDS dest is wave-uniform base + lane*16.
// ---------------------------------------------------------------------------
__device__ __forceinline__ void async_copy16(const void* g, void* lds) {
  __builtin_amdgcn_global_load_lds(
      (const __attribute__((address_space(1))) unsigned int*)g,
      (__attribute__((address_space(3))) unsigned int*)lds, 16, 0, 0);
}

// ---------------------------------------------------------------------------
// bf16 MFMA GEMM (m97 structure): C[M,N] = A[M,K] @ Bt[N,K]^T + bias (+res)
// M=16384, N=K=1024. 128x128 tile, BK=32, 256 thr = 4 waves in 2x2,
// 16x16x32 MFMA, 4x4 tiles/wave, global_load_lds width-16 staging.
// ---------------------------------------------------------------------------
template <bool RES, bool BF16OUT>
__global__ __launch_bounds__(256) void gemm_mfma(const bf16_t* __restrict__ A,
                                                 const bf16_t* __restrict__ Bt,
                                                 const float* __restrict__ bias,
                                                 const float* __restrict__ res,
                                                 float* __restrict__ Cf,
                                                 bf16_t* __restrict__ Cb) {
  constexpr int K = D_DIM, N = D_DIM;
  __shared__ bf16_t As[128 * 32];   // [row m][k] rows of 64B, lane-linear
  __shared__ bf16_t Bs[128 * 32];   // [row n][k]

  const int tid = threadIdx.x;
  const int lane = tid & 63;
  const int wave = tid >> 6;
  const int wm = wave & 1, wn = wave >> 1;
  const int bm = blockIdx.y * 128;
  const int bn = blockIdx.x * 128;
  const int quad = lane >> 4;
  const int l15 = lane & 15;

  f32x4 acc[4][4];
#pragma unroll
  for (int i = 0; i < 4; i++)
#pragma unroll
    for (int j = 0; j < 4; j++) acc[i][j] = (f32x4){0.f, 0.f, 0.f, 0.f};

  // staging: 512 slots of 16B per tile; slot e -> row e>>2, kgroup e&3.
  const int e0 = tid, e1 = tid + 256;
  char* as0 = (char*)As + (size_t)(wave * 64) * 16;          // wave-uniform
  char* as1 = (char*)As + (size_t)(256 + wave * 64) * 16;
  char* bs0 = (char*)Bs + (size_t)(wave * 64) * 16;
  char* bs1 = (char*)Bs + (size_t)(256 + wave * 64) * 16;
  const bf16_t* a0 = A + (size_t)(bm + (e0 >> 2)) * K + (e0 & 3) * 8;
  const bf16_t* a1 = A + (size_t)(bm + (e1 >> 2)) * K + (e1 & 3) * 8;
  const bf16_t* b0 = Bt + (size_t)(bn + (e0 >> 2)) * K + (e0 & 3) * 8;
  const bf16_t* b1 = Bt + (size_t)(bn + (e1 >> 2)) * K + (e1 & 3) * 8;

  for (int k0 = 0; k0 < K; k0 += 32) {
    async_copy16(a0 + k0, as0);
    async_copy16(a1 + k0, as1);
    async_copy16(b0 + k0, bs0);
    async_copy16(b1 + k0, bs1);
    __syncthreads();   // compiler drains vmcnt before barrier

    bf16x8 af[4], bf[4];
#pragma unroll
    for (int t = 0; t < 4; t++) {
      af[t] = *(const bf16x8*)(As + (size_t)(wm * 64 + t * 16 + l15) * 32 + quad * 8);
      bf[t] = *(const bf16x8*)(Bs + (size_t)(wn * 64 + t * 16 + l15) * 32 + quad * 8);
    }
#pragma unroll
    for (int mt = 0; mt < 4; mt++)
#pragma unroll
      for (int nt = 0; nt < 4; nt++)
        acc[mt][nt] =
            __builtin_amdgcn_mfma_f32_16x16x32_bf16(af[mt], bf[nt], acc[mt][nt], 0, 0, 0);
    __syncthreads();
  }

  // epilogue: C/D layout col=lane&15, row=quad*4+reg
  const int baserow = bm + wm * 64;
  const int basecol = bn + wn * 64 + l15;
#pragma unroll
  for (int mt = 0; mt < 4; mt++) {
#pragma unroll
    for (int nt = 0; nt < 4; nt++) {
      const int n = basecol + nt * 16;
      const float bv = bias[n];
#pragma unroll
      for (int r = 0; r < 4; r++) {
        const int m = baserow + mt * 16 + quad * 4 + r;
        float v = acc[mt][nt][r] + bv;
        if (RES) v += res[(size_t)m * N + n];
        if (BF16OUT)
          Cb[(size_t)m * N + n] = (bf16_t)v;
        else
          Cf[(size_t)m * N + n] = v;
      }
    }
  }
}

// ---------------------------------------------------------------------------
// Weight transpose + fp32->bf16: Wt[n][k] = (bf16)W[k][n]. 32x32 LDS tile.
// ---------------------------------------------------------------------------
__global__ __launch_bounds__(256) void transpose_w(const float* __restrict__ W,
                                                   bf16_t* __restrict__ Wt) {
  __shared__ float tile[32][33];
  const int bx = blockIdx.x * 32;  // n
  const int by = blockIdx.y * 32;  // k
  const int tx = threadIdx.x & 31, ty = threadIdx.x >> 5;  // 32 x 8
#pragma unroll
  for (int r = 0; r < 32; r += 8)
    tile[ty + r][tx] = W[(size_t)(by + ty + r) * D_DIM + bx + tx];
  __syncthreads();
#pragma unroll
  for (int r = 0; r < 32; r += 8)
    Wt[(size_t)(bx + ty + r) * D_DIM + by + tx] = (bf16_t)tile[tx][ty + r];
}

// ---------------------------------------------------------------------------
// fp32 -> bf16 elementwise (x conversion), 4 elems/thread.
// ---------------------------------------------------------------------------
__global__ __launch_bounds__(256) void cvt_bf16(const float* __restrict__ in,
                                                bf16_t* __restrict__ outp) {
  const size_t i = (size_t)blockIdx.x * blockDim.x + threadIdx.x;
  const float4 v = ((const float4*)in)[i];
  bf16x4 o;
  o[0] = (bf16_t)v.x; o[1] = (bf16_t)v.y; o[2] = (bf16_t)v.z; o[3] = (bf16_t)v.w;
  ((bf16x4*)outp)[i] = o;
}

// ---------------------------------------------------------------------------
// Fused phasor scan (in-place on value buffer): trig inline, cumsum over the
// 64 rows of each chunk, retrieved = (mr*qc+mi*qs)/sqrt(S).
// ---------------------------------------------------------------------------
__global__ __launch_bounds__(256) void phasor_scan(float* __restrict__ vr,  // value in, ret out
                                                   const float* __restrict__ kp,
                                                   const float* __restrict__ qp) {
  const int half = blockIdx.x;    // 0..1
  const int chunk = blockIdx.y;   // 0..NC-1
  const int b = blockIdx.z;       // 0..B-1
  const int col = half * 512 + threadIdx.x * 2;
  size_t base = ((size_t)(b * S_DIM + chunk * CHUNK)) * D_DIM + col;
  float2 mr = {0.f, 0.f}, mi = {0.f, 0.f};
  const float inv = 0.015625f;  // 1/sqrt(4096)
  for (int s = 0; s < CHUNK; s++) {
    size_t off = base + (size_t)s * D_DIM;
    float2 v = *(const float2*)(vr + off);
    float2 k2 = *(const float2*)(kp + off);
    float2 q2 = *(const float2*)(qp + off);
    float sk, ck, sq, cq;
    sincosf(k2.x, &sk, &ck);
    mr.x = fmaf(v.x, ck, mr.x);
    mi.x = fmaf(v.x, sk, mi.x);
    sincosf(k2.y, &sk, &ck);
    mr.y = fmaf(v.y, ck, mr.y);
    mi.y = fmaf(v.y, sk, mi.y);
    float2 r;
    sincosf(q2.x, &sq, &cq);
    r.x = (mr.x * cq + mi.x * sq) * inv;
    sincosf(q2.y, &sq, &cq);
    r.y = (mr.y * cq + mi.y * sq) * inv;
    *(float2*)(vr + off) = r;
  }
}

// ---------------------------------------------------------------------------
// LayerNorm over D=1024 per row -> bf16 output (feeds final GEMM).
// ---------------------------------------------------------------------------
__global__ __launch_bounds__(256) void layernorm_k(const float* __restrict__ ret,
                                                   const float* __restrict__ g,
                                                   const float* __restrict__ bln,
                                                   bf16_t* __restrict__ outb) {
  const int row = blockIdx.x;
  const float* r = ret + (size_t)row * D_DIM;
  const float4 v = *(const float4*)(r + threadIdx.x * 4);
  float s = v.x + v.y + v.z + v.w;
  float ss = v.x * v.x + v.y * v.y + v.z * v.z + v.w * v.w;
#pragma unroll
  for (int o = 32; o > 0; o >>= 1) {
    s += __shfl_down(s, o);
    ss += __shfl_down(ss, o);
  }
  __shared__ float red[8];
  const int wid = threadIdx.x >> 6;
  if ((threadIdx.x & 63) == 0) {
    red[wid] = s;
    red[4 + wid] = ss;
  }
  __syncthreads();
  if (threadIdx.x == 0) {
    float ts = red[0] + red[1] + red[2] + red[3];
    float tss = red[4] + red[5] + red[6] + red[7];
    float mu = ts * (1.f / D_DIM);
    float var = tss * (1.f / D_DIM) - mu * mu;
    red[0] = mu;
    red[1] = 1.f / sqrtf(var + 1e-5f);
  }
  __syncthreads();
  const float mu = red[0], rs = red[1];
  const float4 gv = *(const float4*)(g + threadIdx.x * 4);
  const float4 bv = *(const float4*)(bln + threadIdx.x * 4);
  bf16x4 o;
  o[0] = (bf16_t)((v.x - mu) * rs * gv.x + bv.x);
  o[1] = (bf16_t)((v.y - mu) * rs * gv.y + bv.y);
  o[2] = (bf16_t)((v.z - mu) * rs * gv.z + bv.z);
  o[3] = (bf16_t)((v.w - mu) * rs * gv.w + bv.w);
  *(bf16x4*)(outb + (size_t)row * D_DIM + threadIdx.x * 4) = o;
}

// ---------------------------------------------------------------------------
// Ortho loss: cos(kp_i)cos(kp_j)+sin(kp_i)sin(kp_j) = cos(kp_i-kp_j).
// ---------------------------------------------------------------------------
__global__ __launch_bounds__(256) void ortho_partial(const float* __restrict__ kp,
                                                     const int* __restrict__ idx,
                                                     float* __restrict__ partial) {
  const int i = blockIdx.x;  // 0..31
  const int b = blockIdx.y;  // 0..3
  const int ri = idx[i];
  const float4 a = *(const float4*)(kp + ((size_t)b * S_DIM + ri) * D_DIM + threadIdx.x * 4);
  float sum = 0.f;
  for (int j = 0; j < 32; j++) {
    if (j == i) continue;
    const int rj = idx[j];
    const float4 c = *(const float4*)(kp + ((size_t)b * S_DIM + rj) * D_DIM + threadIdx.x * 4);
    float d0 = cosf(a.x - c.x);
    float d1 = cosf(a.y - c.y);
    float d2 = cosf(a.z - c.z);
    float d3 = cosf(a.w - c.w);
    sum += d0 * d0 + d1 * d1 + d2 * d2 + d3 * d3;
  }
#pragma unroll
  for (int o = 32; o > 0; o >>= 1) sum += __shfl_down(sum, o);
  __shared__ float red[4];
  if ((threadIdx.x & 63) == 0) red[threadIdx.x >> 6] = sum;
  __syncthreads();
  if (threadIdx.x == 0) partial[b * 32 + i] = red[0] + red[1] + red[2] + red[3];
}

__global__ void ortho_final(const float* __restrict__ partial, float* __restrict__ outp) {
  if (threadIdx.x == 0) {
    double s = 0.0;
    for (int t = 0; t < 128; t++) s += (double)partial[t];
    const double denom = (double)(32 * 31) * 1024.0 + 1e-6;
    outp[0] = (float)(s / denom);
  }
}

// ---------------------------------------------------------------------------
// Orchestration. ws layout (byte offsets, peak 176 MB):
//   [  0, 12M) 6 transposed bf16 weights (2MB each)
//   [ 12M,+)   partial (512B)
//   [ 16, 48M) xb (bf16)          -> later low half of qphase
//   [ 48, 80M) key_b (bf16)       -> later high half of qphase
//   [ 80,112M) query_b (bf16)     -> later ln_b (bf16)
//   [112,176M) kphase (fp32)
//   qphase (fp32) = [16,80M)      (xb,key_b dead by then)
//   value (fp32) lives in d_out; phasor scan runs in-place on d_out.
// ---------------------------------------------------------------------------
extern "C" void kernel_launch(void* const* d_in, const int* in_sizes, int n_in,
                              void* d_out, int out_size, void* d_ws, size_t ws_size,
                              hipStream_t stream) {
  const float* x = (const float*)d_in[0];
  const float* Wk = (const float*)d_in[1];
  const float* bk = (const float*)d_in[2];
  const float* Wv = (const float*)d_in[3];
  const float* bv = (const float*)d_in[4];
  const float* Wq = (const float*)d_in[5];
  const float* bq = (const float*)d_in[6];
  const float* Wkp = (const float*)d_in[7];
  const float* bkp = (const float*)d_in[8];
  const float* Wqp = (const float*)d_in[9];
  const float* bqp = (const float*)d_in[10];
  const float* ln_g = (const float*)d_in[11];
  const float* ln_b = (const float*)d_in[12];
  const float* Wo = (const float*)d_in[13];
  const float* bo = (const float*)d_in[14];
  const int* idx = (const int*)d_in[15];

  float* out = (float*)d_out;
  float* ortho_out = out + (size_t)M_DIM * D_DIM;

  char* ws = (char*)d_ws;
  const size_t MB = 1024 * 1024;
  bf16_t* WkT = (bf16_t*)(ws + 0 * MB);
  bf16_t* WqT = (bf16_t*)(ws + 2 * MB);
  bf16_t* WvT = (bf16_t*)(ws + 4 * MB);
  bf16_t* WkpT = (bf16_t*)(ws + 6 * MB);
  bf16_t* WqpT = (bf16_t*)(ws + 8 * MB);
  bf16_t* WoT = (bf16_t*)(ws + 10 * MB);
  float* partial = (float*)(ws + 12 * MB);
  bf16_t* xb = (bf16_t*)(ws + 16 * MB);
  bf16_t* key_b = (bf16_t*)(ws + 48 * MB);
  bf16_t* query_b = (bf16_t*)(ws + 80 * MB);
  bf16_t* lnb = (bf16_t*)(ws + 80 * MB);   // reuses query_b after it dies
  float* kphase = (float*)(ws + 112 * MB);
  float* qphase = (float*)(ws + 16 * MB);  // reuses xb+key_b after they die

  const dim3 tg(32, 32);
  const dim3 gg(D_DIM / 128, M_DIM / 128);  // (8, 128)

  // 0. weight transposes (bf16) + x conversion
  transpose_w<<<tg, 256, 0, stream>>>(Wk, WkT);
  transpose_w<<<tg, 256, 0, stream>>>(Wq, WqT);
  transpose_w<<<tg, 256, 0, stream>>>(Wv, WvT);
  transpose_w<<<tg, 256, 0, stream>>>(Wkp, WkpT);
  transpose_w<<<tg, 256, 0, stream>>>(Wqp, WqpT);
  transpose_w<<<tg, 256, 0, stream>>>(Wo, WoT);
  cvt_bf16<<<(M_DIM * D_DIM / 4) / 256, 256, 0, stream>>>(x, xb);

  // 1. key_b = xb@Wk (bf16 out)
  gemm_mfma<false, true><<<gg, 256, 0, stream>>>(xb, WkT, bk, nullptr, nullptr, key_b);
  // 2. query_b = xb@Wq (bf16 out)
  gemm_mfma<false, true><<<gg, 256, 0, stream>>>(xb, WqT, bq, nullptr, nullptr, query_b);
  // 3. value = xb@Wv -> d_out (fp32); xb dead after
  gemm_mfma<false, false><<<gg, 256, 0, stream>>>(xb, WvT, bv, nullptr, out, nullptr);
  // 4. kphase = key_b@Wkp (fp32); key_b dead after
  gemm_mfma<false, false><<<gg, 256, 0, stream>>>(key_b, WkpT, bkp, nullptr, kphase, nullptr);
  // 5. qphase = query_b@Wqp (fp32, into xb+key_b slots); query_b dead after
  gemm_mfma<false, false><<<gg, 256, 0, stream>>>(query_b, WqpT, bqp, nullptr, qphase, nullptr);
  // 6. ortho from kphase
  ortho_partial<<<dim3(32, B_DIM), 256, 0, stream>>>(kphase, idx, partial);
  ortho_final<<<1, 64, 0, stream>>>(partial, ortho_out);
  // 7. fused trig + chunk cumsum + retrieve, in-place on d_out
  phasor_scan<<<dim3(2, NC, B_DIM), 256, 0, stream>>>(out, kphase, qphase);
  // 8. LayerNorm -> lnb (bf16)
  layernorm_k<<<M_DIM, 256, 0, stream>>>(out, ln_g, ln_b, lnb);
  // 9. out = x + lnb@Wo + bo
  gemm_mfma<true, false><<<gg, 256, 0, stream>>>(lnb, WoT, bo, x, out, nullptr);
}

// Round 3
// 563.617 us; speedup vs baseline: 4.5697x; 1.1314x over previous
//
#include <hip/hip_runtime.h>
#include <math.h>

#define D_DIM 1024
#define S_DIM 4096
#define B_DIM 4
#define CHUNK 64
#define NC (S_DIM / CHUNK)
#define M_DIM (B_DIM * S_DIM)   // 16384 rows

typedef __bf16 bf16_t;
typedef __attribute__((ext_vector_type(8))) __bf16 bf16x8;
typedef __attribute__((ext_vector_type(4))) __bf16 bf16x4;
typedef __attribute__((ext_vector_type(2))) __bf16 bf16x2;
typedef __attribute__((ext_vector_type(4))) float f32x4;

// ---------------------------------------------------------------------------
// async 16B/lane global->LDS. LDS dest is wave-uniform base + lane*16.
// ---------------------------------------------------------------------------
__device__ __forceinline__ void async_copy16(const void* g, void* lds) {
  __builtin_amdgcn_global_load_lds(
      (const __attribute__((address_space(1))) unsigned int*)g,
      (__attribute__((address_space(3))) unsigned int*)lds, 16, 0, 0);
}

// ---------------------------------------------------------------------------
// bf16 MFMA GEMM (m97 structure), 128x128 tile, BK=32, 4 waves 2x2,
// 16x16x32 MFMA 4x4/wave, global_load_lds width-16 staging.
// MODE 0 (QKV):   A[16384,1024] @ Bt[3072,1024]^T; out 3 bf16 tensors
//                 [t][16384][1024] at Cb0 + t*M*D (t = bn>>10, block-uniform)
// MODE 1 (PHASE): A[32768,1024] (key||query); t = blockIdx.y>>7 selects
//                 Bt half, bias half, Cb0(kp)/Cb1(qp); bf16 out
// MODE 2 (FINAL): A[16384,1024]; fp32 out Cf = A@Bt^T + bias + res
// ---------------------------------------------------------------------------
template <int MODE>
__global__ __launch_bounds__(256) void gemm_mfma(const bf16_t* __restrict__ A,
                                                 const bf16_t* __restrict__ Bt,
                                                 const float* __restrict__ bias,
                                                 const float* __restrict__ res,
                                                 float* __restrict__ Cf,
                                                 bf16_t* __restrict__ Cb0,
                                                 bf16_t* __restrict__ Cb1) {
  constexpr int K = D_DIM;
  __shared__ bf16_t As[128 * 32];   // [row m][k], lane-linear 16B slots
  __shared__ bf16_t Bs[128 * 32];   // [row n][k]

  const int tid = threadIdx.x;
  const int lane = tid & 63;
  const int wave = tid >> 6;
  const int wm = wave & 1, wn = wave >> 1;
  const int bm = blockIdx.y * 128;
  const int bn = blockIdx.x * 128;
  const int quad = lane >> 4;
  const int l15 = lane & 15;

  const bf16_t* BtP = Bt;
  const float* biasP = bias;
  bf16_t* outB = Cb0;
  if (MODE == 1) {
    const int tsel = blockIdx.y >> 7;   // 0=kp, 1=qp (block-uniform)
    BtP = Bt + (size_t)tsel * D_DIM * D_DIM;
    biasP = bias + tsel * D_DIM;
    outB = tsel ? Cb1 : Cb0;
  }

  f32x4 acc[4][4];
#pragma unroll
  for (int i = 0; i < 4; i++)
#pragma unroll
    for (int j = 0; j < 4; j++) acc[i][j] = (f32x4){0.f, 0.f, 0.f, 0.f};

  // staging: 512 slots of 16B per tile; slot e -> row e>>2, kgroup e&3.
  const int e0 = tid, e1 = tid + 256;
  char* as0 = (char*)As + (size_t)(wave * 64) * 16;          // wave-uniform
  char* as1 = (char*)As + (size_t)(256 + wave * 64) * 16;
  char* bs0 = (char*)Bs + (size_t)(wave * 64) * 16;
  char* bs1 = (char*)Bs + (size_t)(256 + wave * 64) * 16;
  const bf16_t* a0 = A + (size_t)(bm + (e0 >> 2)) * K + (e0 & 3) * 8;
  const bf16_t* a1 = A + (size_t)(bm + (e1 >> 2)) * K + (e1 & 3) * 8;
  const bf16_t* b0 = BtP + (size_t)(bn + (e0 >> 2)) * K + (e0 & 3) * 8;
  const bf16_t* b1 = BtP + (size_t)(bn + (e1 >> 2)) * K + (e1 & 3) * 8;

  for (int k0 = 0; k0 < K; k0 += 32) {
    async_copy16(a0 + k0, as0);
    async_copy16(a1 + k0, as1);
    async_copy16(b0 + k0, bs0);
    async_copy16(b1 + k0, bs1);
    __syncthreads();

    bf16x8 af[4], bfr[4];
#pragma unroll
    for (int t = 0; t < 4; t++) {
      af[t] = *(const bf16x8*)(As + (size_t)(wm * 64 + t * 16 + l15) * 32 + quad * 8);
      bfr[t] = *(const bf16x8*)(Bs + (size_t)(wn * 64 + t * 16 + l15) * 32 + quad * 8);
    }
#pragma unroll
    for (int mt = 0; mt < 4; mt++)
#pragma unroll
      for (int nt = 0; nt < 4; nt++)
        acc[mt][nt] =
            __builtin_amdgcn_mfma_f32_16x16x32_bf16(af[mt], bfr[nt], acc[mt][nt], 0, 0, 0);
    __syncthreads();
  }

  // epilogue: C/D layout col=lane&15, row=quad*4+reg
  const int baserow = bm + wm * 64;
  const int basecol = bn + wn * 64 + l15;
  // MODE 0: tensor select + column fold (block-uniform t)
  size_t obase = 0;
  if (MODE == 0) obase = (size_t)(bn >> 10) * M_DIM * D_DIM;
#pragma unroll
  for (int mt = 0; mt < 4; mt++) {
#pragma unroll
    for (int nt = 0; nt < 4; nt++) {
      const int n = basecol + nt * 16;
      const float bv = biasP[MODE == 0 ? n : (n & 1023)];
      const int col = n & 1023;
#pragma unroll
      for (int r = 0; r < 4; r++) {
        const int m = baserow + mt * 16 + quad * 4 + r;
        float v = acc[mt][nt][r] + bv;
        if (MODE == 2) {
          v += res[(size_t)m * D_DIM + n];
          Cf[(size_t)m * D_DIM + n] = v;
        } else if (MODE == 0) {
          Cb0[obase + (size_t)m * D_DIM + col] = (bf16_t)v;
        } else {
          outB[(size_t)(m & 16383) * D_DIM + col] = (bf16_t)v;
        }
      }
    }
  }
}

// ---------------------------------------------------------------------------
// Weight transpose + fp32->bf16: Wt[n][k] = (bf16)W[k][n]. 32x32 LDS tile.
// ---------------------------------------------------------------------------
__global__ __launch_bounds__(256) void transpose_w(const float* __restrict__ W,
                                                   bf16_t* __restrict__ Wt) {
  __shared__ float tile[32][33];
  const int bx = blockIdx.x * 32;  // n
  const int by = blockIdx.y * 32;  // k
  const int tx = threadIdx.x & 31, ty = threadIdx.x >> 5;  // 32 x 8
#pragma unroll
  for (int r = 0; r < 32; r += 8)
    tile[ty + r][tx] = W[(size_t)(by + ty + r) * D_DIM + bx + tx];
  __syncthreads();
#pragma unroll
  for (int r = 0; r < 32; r += 8)
    Wt[(size_t)(bx + ty + r) * D_DIM + by + tx] = (bf16_t)tile[tx][ty + r];
}

__global__ __launch_bounds__(256) void concat_bias(const float* __restrict__ bk,
                                                   const float* __restrict__ bq,
                                                   const float* __restrict__ bv,
                                                   const float* __restrict__ bkp,
                                                   const float* __restrict__ bqp,
                                                   float* __restrict__ qkvb,
                                                   float* __restrict__ pb) {
  const int i = blockIdx.x * 256 + threadIdx.x;  // grid 4 -> 0..1023
  qkvb[i] = bk[i];
  qkvb[1024 + i] = bq[i];
  qkvb[2048 + i] = bv[i];
  pb[i] = bkp[i];
  pb[1024 + i] = bqp[i];
}

// ---------------------------------------------------------------------------
// fp32 -> bf16 elementwise (x conversion), 4 elems/thread.
// ---------------------------------------------------------------------------
__global__ __launch_bounds__(256) void cvt_bf16(const float* __restrict__ in,
                                                bf16_t* __restrict__ outp) {
  const size_t i = (size_t)blockIdx.x * blockDim.x + threadIdx.x;
  const float4 v = ((const float4*)in)[i];
  bf16x4 o;
  o[0] = (bf16_t)v.x; o[1] = (bf16_t)v.y; o[2] = (bf16_t)v.z; o[3] = (bf16_t)v.w;
  ((bf16x4*)outp)[i] = o;
}

// ---------------------------------------------------------------------------
// Fused phasor scan, all-bf16 I/O: trig inline (fp32 math), cumsum over 64
// rows of each chunk, ret = (mr*qc+mi*qs)/sqrt(S) stored bf16.
// ---------------------------------------------------------------------------
__global__ __launch_bounds__(256) void phasor_scan(const bf16_t* __restrict__ vb,
                                                   const bf16_t* __restrict__ kp,
                                                   const bf16_t* __restrict__ qp,
                                                   bf16_t* __restrict__ ret) {
  const int half = blockIdx.x;    // 0..1
  const int chunk = blockIdx.y;   // 0..NC-1
  const int b = blockIdx.z;       // 0..B-1
  const int col = half * 512 + threadIdx.x * 2;
  size_t base = ((size_t)(b * S_DIM + chunk * CHUNK)) * D_DIM + col;
  float2 mr = {0.f, 0.f}, mi = {0.f, 0.f};
  const float inv = 0.015625f;  // 1/sqrt(4096)
  for (int s = 0; s < CHUNK; s++) {
    size_t off = base + (size_t)s * D_DIM;
    bf16x2 v2 = *(const bf16x2*)(vb + off);
    bf16x2 k2 = *(const bf16x2*)(kp + off);
    bf16x2 q2 = *(const bf16x2*)(qp + off);
    float sk, ck, sq, cq;
    sincosf((float)k2[0], &sk, &ck);
    mr.x = fmaf((float)v2[0], ck, mr.x);
    mi.x = fmaf((float)v2[0], sk, mi.x);
    sincosf((float)k2[1], &sk, &ck);
    mr.y = fmaf((float)v2[1], ck, mr.y);
    mi.y = fmaf((float)v2[1], sk, mi.y);
    bf16x2 r;
    sincosf((float)q2[0], &sq, &cq);
    r[0] = (bf16_t)((mr.x * cq + mi.x * sq) * inv);
    sincosf((float)q2[1], &sq, &cq);
    r[1] = (bf16_t)((mr.y * cq + mi.y * sq) * inv);
    *(bf16x2*)(ret + off) = r;
  }
}

// ---------------------------------------------------------------------------
// LayerNorm over D=1024 per row, bf16 in -> bf16 out.
// ---------------------------------------------------------------------------
__global__ __launch_bounds__(256) void layernorm_k(const bf16_t* __restrict__ ret,
                                                   const float* __restrict__ g,
                                                   const float* __restrict__ bln,
                                                   bf16_t* __restrict__ outb) {
  const int row = blockIdx.x;
  const bf16x4 rv = *(const bf16x4*)(ret + (size_t)row * D_DIM + threadIdx.x * 4);
  float4 v;
  v.x = (float)rv[0]; v.y = (float)rv[1]; v.z = (float)rv[2]; v.w = (float)rv[3];
  float s = v.x + v.y + v.z + v.w;
  float ss = v.x * v.x + v.y * v.y + v.z * v.z + v.w * v.w;
#pragma unroll
  for (int o = 32; o > 0; o >>= 1) {
    s += __shfl_down(s, o);
    ss += __shfl_down(ss, o);
  }
  __shared__ float red[8];
  const int wid = threadIdx.x >> 6;
  if ((threadIdx.x & 63) == 0) {
    red[wid] = s;
    red[4 + wid] = ss;
  }
  __syncthreads();
  if (threadIdx.x == 0) {
    float ts = red[0] + red[1] + red[2] + red[3];
    float tss = red[4] + red[5] + red[6] + red[7];
    float mu = ts * (1.f / D_DIM);
    float var = tss * (1.f / D_DIM) - mu * mu;
    red[0] = mu;
    red[1] = 1.f / sqrtf(var + 1e-5f);
  }
  __syncthreads();
  const float mu = red[0], rs = red[1];
  const float4 gv = *(const float4*)(g + threadIdx.x * 4);
  const float4 bv = *(const float4*)(bln + threadIdx.x * 4);
  bf16x4 o;
  o[0] = (bf16_t)((v.x - mu) * rs * gv.x + bv.x);
  o[1] = (bf16_t)((v.y - mu) * rs * gv.y + bv.y);
  o[2] = (bf16_t)((v.z - mu) * rs * gv.z + bv.z);
  o[3] = (bf16_t)((v.w - mu) * rs * gv.w + bv.w);
  *(bf16x4*)(outb + (size_t)row * D_DIM + threadIdx.x * 4) = o;
}

// ---------------------------------------------------------------------------
// Ortho loss from bf16 kphase: cos(kp_i)cos(kp_j)+sin..sin.. = cos(kp_i-kp_j)
// ---------------------------------------------------------------------------
__global__ __launch_bounds__(256) void ortho_partial(const bf16_t* __restrict__ kp,
                                                     const int* __restrict__ idx,
                                                     float* __restrict__ partial) {
  const int i = blockIdx.x;  // 0..31
  const int b = blockIdx.y;  // 0..3
  const int ri = idx[i];
  const bf16x4 ab = *(const bf16x4*)(kp + ((size_t)b * S_DIM + ri) * D_DIM + threadIdx.x * 4);
  float a0 = (float)ab[0], a1 = (float)ab[1], a2 = (float)ab[2], a3 = (float)ab[3];
  float sum = 0.f;
  for (int j = 0; j < 32; j++) {
    if (j == i) continue;
    const int rj = idx[j];
    const bf16x4 cb = *(const bf16x4*)(kp + ((size_t)b * S_DIM + rj) * D_DIM + threadIdx.x * 4);
    float d0 = cosf(a0 - (float)cb[0]);
    float d1 = cosf(a1 - (float)cb[1]);
    float d2 = cosf(a2 - (float)cb[2]);
    float d3 = cosf(a3 - (float)cb[3]);
    sum += d0 * d0 + d1 * d1 + d2 * d2 + d3 * d3;
  }
#pragma unroll
  for (int o = 32; o > 0; o >>= 1) sum += __shfl_down(sum, o);
  __shared__ float red[4];
  if ((threadIdx.x & 63) == 0) red[threadIdx.x >> 6] = sum;
  __syncthreads();
  if (threadIdx.x == 0) partial[b * 32 + i] = red[0] + red[1] + red[2] + red[3];
}

__global__ void ortho_final(const float* __restrict__ partial, float* __restrict__ outp) {
  if (threadIdx.x == 0) {
    double s = 0.0;
    for (int t = 0; t < 128; t++) s += (double)partial[t];
    const double denom = (double)(32 * 31) * 1024.0 + 1e-6;
    outp[0] = (float)(s / denom);
  }
}

// ---------------------------------------------------------------------------
// Orchestration. ws layout (byte offsets, peak 176 MB):
//   [  0,  6M) QKVT bf16 [3072,1024]       [  6, 10M) PhaseT bf16 [2,1024,1024]
//   [ 10, 12M) WoT bf16                    [ 12M+..)  qkv_bias, phase_bias, partial
//   [ 16, 48M) xb        -> qp_b           [ 48, 80M) key_b  -> ret_b
//   [ 80,112M) query_b   -> lnb            [112,144M) value_b
//   [144,176M) kp_b
// ---------------------------------------------------------------------------
extern "C" void kernel_launch(void* const* d_in, const int* in_sizes, int n_in,
                              void* d_out, int out_size, void* d_ws, size_t ws_size,
                              hipStream_t stream) {
  const float* x = (const float*)d_in[0];
  const float* Wk = (const float*)d_in[1];
  const float* bk = (const float*)d_in[2];
  const float* Wv = (const float*)d_in[3];
  const float* bv = (const float*)d_in[4];
  const float* Wq = (const float*)d_in[5];
  const float* bq = (const float*)d_in[6];
  const float* Wkp = (const float*)d_in[7];
  const float* bkp = (const float*)d_in[8];
  const float* Wqp = (const float*)d_in[9];
  const float* bqp = (const float*)d_in[10];
  const float* ln_g = (const float*)d_in[11];
  const float* ln_b = (const float*)d_in[12];
  const float* Wo = (const float*)d_in[13];
  const float* bo = (const float*)d_in[14];
  const int* idx = (const int*)d_in[15];

  float* out = (float*)d_out;
  float* ortho_out = out + (size_t)M_DIM * D_DIM;

  char* ws = (char*)d_ws;
  const size_t MB = 1024 * 1024;
  bf16_t* QKVT = (bf16_t*)(ws + 0 * MB);    // [3072,1024]
  bf16_t* PhaseT = (bf16_t*)(ws + 6 * MB);  // [2,1024,1024]
  bf16_t* WoT = (bf16_t*)(ws + 10 * MB);
  float* qkv_bias = (float*)(ws + 12 * MB);        // 3072
  float* phase_bias = (float*)(ws + 12 * MB + 16 * 1024);  // 2048
  float* partial = (float*)(ws + 12 * MB + 32 * 1024);     // 128
  bf16_t* xb = (bf16_t*)(ws + 16 * MB);
  bf16_t* key_b = (bf16_t*)(ws + 48 * MB);   // QKV out base: [3][M][D]
  bf16_t* query_b = (bf16_t*)(ws + 80 * MB);
  bf16_t* value_b = (bf16_t*)(ws + 112 * MB);
  bf16_t* kp_b = (bf16_t*)(ws + 144 * MB);
  bf16_t* qp_b = (bf16_t*)(ws + 16 * MB);    // reuses xb
  bf16_t* ret_b = (bf16_t*)(ws + 48 * MB);   // reuses key_b
  bf16_t* lnb = (bf16_t*)(ws + 80 * MB);     // reuses query_b
  (void)query_b; (void)value_b;

  const dim3 tg(32, 32);

  // 0. weight prep + x conversion
  transpose_w<<<tg, 256, 0, stream>>>(Wk, QKVT);
  transpose_w<<<tg, 256, 0, stream>>>(Wq, QKVT + (size_t)D_DIM * D_DIM);
  transpose_w<<<tg, 256, 0, stream>>>(Wv, QKVT + (size_t)2 * D_DIM * D_DIM);
  transpose_w<<<tg, 256, 0, stream>>>(Wkp, PhaseT);
  transpose_w<<<tg, 256, 0, stream>>>(Wqp, PhaseT + (size_t)D_DIM * D_DIM);
  transpose_w<<<tg, 256, 0, stream>>>(Wo, WoT);
  concat_bias<<<4, 256, 0, stream>>>(bk, bq, bv, bkp, bqp, qkv_bias, phase_bias);
  cvt_bf16<<<(M_DIM * D_DIM / 4) / 256, 256, 0, stream>>>(x, xb);

  // 1. fused QKV: [key|query|value] = xb @ QKVT^T   (grid 24 x 128)
  gemm_mfma<0><<<dim3(3 * D_DIM / 128, M_DIM / 128), 256, 0, stream>>>(
      xb, QKVT, qkv_bias, nullptr, nullptr, key_b, nullptr);
  // 2. batched phases: kp = key@Wkp, qp = query@Wqp  (grid 8 x 256; xb dead)
  gemm_mfma<1><<<dim3(D_DIM / 128, 2 * M_DIM / 128), 256, 0, stream>>>(
      key_b, PhaseT, phase_bias, nullptr, nullptr, kp_b, qp_b);
  // 3. ortho from kp_b
  ortho_partial<<<dim3(32, B_DIM), 256, 0, stream>>>(kp_b, idx, partial);
  ortho_final<<<1, 64, 0, stream>>>(partial, ortho_out);
  // 4. fused trig + chunk cumsum + retrieve -> ret_b (key region dead)
  phasor_scan<<<dim3(2, NC, B_DIM), 256, 0, stream>>>(value_b, kp_b, qp_b, ret_b);
  // 5. LayerNorm -> lnb (query region dead)
  layernorm_k<<<M_DIM, 256, 0, stream>>>(ret_b, ln_g, ln_b, lnb);
  // 6. out = x + lnb@Wo + bo
  gemm_mfma<2><<<dim3(D_DIM / 128, M_DIM / 128), 256, 0, stream>>>(
      lnb, WoT, bo, x, out, nullptr, nullptr);
}

// Round 4
// 496.433 us; speedup vs baseline: 5.1882x; 1.1353x over previous
//
#include <hip/hip_runtime.h>
#include <math.h>

#define D_DIM 1024
#define S_DIM 4096
#define B_DIM 4
#define CHUNK 64
#define NC (S_DIM / CHUNK)
#define M_DIM (B_DIM * S_DIM)   // 16384 rows
#define MD ((size_t)M_DIM * D_DIM)

typedef __bf16 bf16_t;
typedef __attribute__((ext_vector_type(8))) __bf16 bf16x8;
typedef __attribute__((ext_vector_type(4))) __bf16 bf16x4;
typedef __attribute__((ext_vector_type(2))) __bf16 bf16x2;
typedef __attribute__((ext_vector_type(4))) float f32x4;

// ---------------------------------------------------------------------------
// async 16B/lane global->LDS. LDS dest is wave-uniform base + lane*16.
// ---------------------------------------------------------------------------
__device__ __forceinline__ void async_copy16(const void* g, void* lds) {
  __builtin_amdgcn_global_load_lds(
      (const __attribute__((address_space(1))) unsigned int*)g,
      (__attribute__((address_space(3))) unsigned int*)lds, 16, 0, 0);
}

// ---------------------------------------------------------------------------
// bf16 MFMA GEMM (m97 structure), 128x128 tile, BK=32, 4 waves 2x2,
// 16x16x32 MFMA 4x4/wave, global_load_lds width-16 staging.
// 1-D grid with XCD swizzle: xcd=bid&7 owns NB_M/8 consecutive m-rows so
// each A row-tile stays in one XCD's L2 across all its n-blocks.
// MODE 0 (MEGA):  A=xb[16384,1024] @ QKVT[3072,1024]^T + fbias;
//                 out bf16 [t][16384][1024], t=bn>>10 (0=value,1=kp,2=qp)
// MODE 2 (FINAL): fp32 out Cf = A@Bt^T + bias + res
// MODE 3 (WFUSE): A=WkpT||WqpT [2048,1024]; tsel=bm>>10 selects Bt half
//                 (Wk_b/Wq_b) and out half; out bf16 [2][1024][1024], no bias
// ---------------------------------------------------------------------------
template <int MODE>
__global__ __launch_bounds__(256) void gemm_mfma(const bf16_t* __restrict__ A,
                                                 const bf16_t* __restrict__ Bt,
                                                 const float* __restrict__ bias,
                                                 const float* __restrict__ res,
                                                 float* __restrict__ Cf,
                                                 bf16_t* __restrict__ Cb) {
  constexpr int K = D_DIM;
  constexpr int NB_N = (MODE == 0) ? 24 : 8;
  constexpr int NB_M = (MODE == 3) ? 16 : 128;
  __shared__ bf16_t As[128 * 32];   // [row m][k], lane-linear 16B slots
  __shared__ bf16_t Bs[128 * 32];   // [row n][k]

  const int bid = blockIdx.x;
  const int xcd = bid & 7;
  const int slot = bid >> 3;
  const int bm = (xcd * (NB_M / 8) + slot / NB_N) * 128;
  const int bn = (slot % NB_N) * 128;

  const int tid = threadIdx.x;
  const int lane = tid & 63;
  const int wave = tid >> 6;
  const int wm = wave & 1, wn = wave >> 1;
  const int quad = lane >> 4;
  const int l15 = lane & 15;

  const bf16_t* BtP = Bt;
  if (MODE == 3) BtP = Bt + (size_t)(bm >> 10) * D_DIM * D_DIM;

  f32x4 acc[4][4];
#pragma unroll
  for (int i = 0; i < 4; i++)
#pragma unroll
    for (int j = 0; j < 4; j++) acc[i][j] = (f32x4){0.f, 0.f, 0.f, 0.f};

  // staging: 512 slots of 16B per tile; slot e -> row e>>2, kgroup e&3.
  const int e0 = tid, e1 = tid + 256;
  char* as0 = (char*)As + (size_t)(wave * 64) * 16;          // wave-uniform
  char* as1 = (char*)As + (size_t)(256 + wave * 64) * 16;
  char* bs0 = (char*)Bs + (size_t)(wave * 64) * 16;
  char* bs1 = (char*)Bs + (size_t)(256 + wave * 64) * 16;
  const bf16_t* a0 = A + (size_t)(bm + (e0 >> 2)) * K + (e0 & 3) * 8;
  const bf16_t* a1 = A + (size_t)(bm + (e1 >> 2)) * K + (e1 & 3) * 8;
  const bf16_t* b0 = BtP + (size_t)(bn + (e0 >> 2)) * K + (e0 & 3) * 8;
  const bf16_t* b1 = BtP + (size_t)(bn + (e1 >> 2)) * K + (e1 & 3) * 8;

  for (int k0 = 0; k0 < K; k0 += 32) {
    async_copy16(a0 + k0, as0);
    async_copy16(a1 + k0, as1);
    async_copy16(b0 + k0, bs0);
    async_copy16(b1 + k0, bs1);
    __syncthreads();

    bf16x8 af[4], bfr[4];
#pragma unroll
    for (int t = 0; t < 4; t++) {
      af[t] = *(const bf16x8*)(As + (size_t)(wm * 64 + t * 16 + l15) * 32 + quad * 8);
      bfr[t] = *(const bf16x8*)(Bs + (size_t)(wn * 64 + t * 16 + l15) * 32 + quad * 8);
    }
#pragma unroll
    for (int mt = 0; mt < 4; mt++)
#pragma unroll
      for (int nt = 0; nt < 4; nt++)
        acc[mt][nt] =
            __builtin_amdgcn_mfma_f32_16x16x32_bf16(af[mt], bfr[nt], acc[mt][nt], 0, 0, 0);
    __syncthreads();
  }

  // epilogue: C/D layout col=lane&15, row=quad*4+reg
  const int baserow = bm + wm * 64;
  const int basecol = bn + wn * 64 + l15;
#pragma unroll
  for (int mt = 0; mt < 4; mt++) {
#pragma unroll
    for (int nt = 0; nt < 4; nt++) {
      const int n = basecol + nt * 16;
      const float bv = (MODE == 3) ? 0.f : bias[n];
#pragma unroll
      for (int r = 0; r < 4; r++) {
        const int m = baserow + mt * 16 + quad * 4 + r;
        float v = acc[mt][nt][r] + bv;
        if (MODE == 2) {
          v += res[(size_t)m * D_DIM + n];
          Cf[(size_t)m * D_DIM + n] = v;
        } else if (MODE == 0) {
          Cb[(size_t)(bn >> 10) * MD + (size_t)m * D_DIM + (n & 1023)] = (bf16_t)v;
        } else {  // MODE 3
          Cb[(size_t)(bm >> 10) * D_DIM * D_DIM + (size_t)(m & 1023) * D_DIM + n] =
              (bf16_t)v;
        }
      }
    }
  }
}

// ---------------------------------------------------------------------------
// Batched weight transpose + fp32->bf16: Wt[n][k] = (bf16)W[k][n], 4 weights.
// ---------------------------------------------------------------------------
__global__ __launch_bounds__(256) void prep_transpose(
    const float* __restrict__ s0, const float* __restrict__ s1,
    const float* __restrict__ s2, const float* __restrict__ s3,
    bf16_t* __restrict__ d0, bf16_t* __restrict__ d1,
    bf16_t* __restrict__ d2, bf16_t* __restrict__ d3) {
  const float* srcs[4] = {s0, s1, s2, s3};
  bf16_t* dsts[4] = {d0, d1, d2, d3};
  const float* W = srcs[blockIdx.z];
  bf16_t* Wt = dsts[blockIdx.z];
  __shared__ float tile[32][33];
  const int bx = blockIdx.x * 32;  // n
  const int by = blockIdx.y * 32;  // k
  const int tx = threadIdx.x & 31, ty = threadIdx.x >> 5;  // 32 x 8
#pragma unroll
  for (int r = 0; r < 32; r += 8)
    tile[ty + r][tx] = W[(size_t)(by + ty + r) * D_DIM + bx + tx];
  __syncthreads();
#pragma unroll
  for (int r = 0; r < 32; r += 8)
    Wt[(size_t)(bx + ty + r) * D_DIM + by + tx] = (bf16_t)tile[tx][ty + r];
}

// ---------------------------------------------------------------------------
// Batched fp32->bf16 cast: x (16M) | Wk (1M) | Wq (1M), 4 elems/thread.
// ---------------------------------------------------------------------------
__global__ __launch_bounds__(256) void prep_cast(const float* __restrict__ x,
                                                 const float* __restrict__ Wk,
                                                 const float* __restrict__ Wq,
                                                 bf16_t* __restrict__ xb,
                                                 bf16_t* __restrict__ wkb,
                                                 bf16_t* __restrict__ wqb) {
  size_t i = (size_t)blockIdx.x * 256 + threadIdx.x;  // float4 group index
  const float* src;
  bf16_t* dst;
  size_t off;
  if (i < 4194304) { src = x; dst = xb; off = i; }
  else if (i < 4456448) { src = Wk; dst = wkb; off = i - 4194304; }
  else { src = Wq; dst = wqb; off = i - 4456448; }
  const float4 v = ((const float4*)src)[off];
  bf16x4 o;
  o[0] = (bf16_t)v.x; o[1] = (bf16_t)v.y; o[2] = (bf16_t)v.z; o[3] = (bf16_t)v.w;
  ((bf16x4*)dst)[off] = o;
}

// ---------------------------------------------------------------------------
// Fused bias: fb[0:1024)=bv; fb[1024+c)=bk@Wkp[:,c]+bkp[c]; fb[2048+c) same
// for q. fp32 exact.
// ---------------------------------------------------------------------------
__global__ __launch_bounds__(256) void fused_bias_k(
    const float* __restrict__ bv, const float* __restrict__ bk,
    const float* __restrict__ bkp, const float* __restrict__ bq,
    const float* __restrict__ bqp, const float* __restrict__ Wkp,
    const float* __restrict__ Wqp, float* __restrict__ fb) {
  const int n = blockIdx.x * 256 + threadIdx.x;  // 0..3071
  const int t = n >> 10, c = n & 1023;
  if (t == 0) {
    fb[n] = bv[c];
    return;
  }
  const float* W = (t == 1) ? Wkp : Wqp;
  const float* b1 = (t == 1) ? bk : bq;
  const float* b2 = (t == 1) ? bkp : bqp;
  float s = b2[c];
  for (int k = 0; k < D_DIM; k++) s = fmaf(b1[k], W[(size_t)k * D_DIM + c], s);
  fb[n] = s;
}

// ---------------------------------------------------------------------------
// Fused phasor scan, all-bf16 I/O: trig inline (fp32 math), cumsum over 64
// rows of each chunk, ret = (mr*qc+mi*qs)/sqrt(S) stored bf16.
// ---------------------------------------------------------------------------
__global__ __launch_bounds__(256) void phasor_scan(const bf16_t* __restrict__ vb,
                                                   const bf16_t* __restrict__ kp,
                                                   const bf16_t* __restrict__ qp,
                                                   bf16_t* __restrict__ ret) {
  const int half = blockIdx.x;    // 0..1
  const int chunk = blockIdx.y;   // 0..NC-1
  const int b = blockIdx.z;       // 0..B-1
  const int col = half * 512 + threadIdx.x * 2;
  size_t base = ((size_t)(b * S_DIM + chunk * CHUNK)) * D_DIM + col;
  float2 mr = {0.f, 0.f}, mi = {0.f, 0.f};
  const float inv = 0.015625f;  // 1/sqrt(4096)
  for (int s = 0; s < CHUNK; s++) {
    size_t off = base + (size_t)s * D_DIM;
    bf16x2 v2 = *(const bf16x2*)(vb + off);
    bf16x2 k2 = *(const bf16x2*)(kp + off);
    bf16x2 q2 = *(const bf16x2*)(qp + off);
    float sk, ck, sq, cq;
    sincosf((float)k2[0], &sk, &ck);
    mr.x = fmaf((float)v2[0], ck, mr.x);
    mi.x = fmaf((float)v2[0], sk, mi.x);
    sincosf((float)k2[1], &sk, &ck);
    mr.y = fmaf((float)v2[1], ck, mr.y);
    mi.y = fmaf((float)v2[1], sk, mi.y);
    bf16x2 r;
    sincosf((float)q2[0], &sq, &cq);
    r[0] = (bf16_t)((mr.x * cq + mi.x * sq) * inv);
    sincosf((float)q2[1], &sq, &cq);
    r[1] = (bf16_t)((mr.y * cq + mi.y * sq) * inv);
    *(bf16x2*)(ret + off) = r;
  }
}

// ---------------------------------------------------------------------------
// LayerNorm over D=1024 per row, bf16 in -> bf16 out.
// ---------------------------------------------------------------------------
__global__ __launch_bounds__(256) void layernorm_k(const bf16_t* __restrict__ ret,
                                                   const float* __restrict__ g,
                                                   const float* __restrict__ bln,
                                                   bf16_t* __restrict__ outb) {
  const int row = blockIdx.x;
  const bf16x4 rv = *(const bf16x4*)(ret + (size_t)row * D_DIM + threadIdx.x * 4);
  float4 v;
  v.x = (float)rv[0]; v.y = (float)rv[1]; v.z = (float)rv[2]; v.w = (float)rv[3];
  float s = v.x + v.y + v.z + v.w;
  float ss = v.x * v.x + v.y * v.y + v.z * v.z + v.w * v.w;
#pragma unroll
  for (int o = 32; o > 0; o >>= 1) {
    s += __shfl_down(s, o);
    ss += __shfl_down(ss, o);
  }
  __shared__ float red[8];
  const int wid = threadIdx.x >> 6;
  if ((threadIdx.x & 63) == 0) {
    red[wid] = s;
    red[4 + wid] = ss;
  }
  __syncthreads();
  if (threadIdx.x == 0) {
    float ts = red[0] + red[1] + red[2] + red[3];
    float tss = red[4] + red[5] + red[6] + red[7];
    float mu = ts * (1.f / D_DIM);
    float var = tss * (1.f / D_DIM) - mu * mu;
    red[0] = mu;
    red[1] = 1.f / sqrtf(var + 1e-5f);
  }
  __syncthreads();
  const float mu = red[0], rs = red[1];
  const float4 gv = *(const float4*)(g + threadIdx.x * 4);
  const float4 bv = *(const float4*)(bln + threadIdx.x * 4);
  bf16x4 o;
  o[0] = (bf16_t)((v.x - mu) * rs * gv.x + bv.x);
  o[1] = (bf16_t)((v.y - mu) * rs * gv.y + bv.y);
  o[2] = (bf16_t)((v.z - mu) * rs * gv.z + bv.z);
  o[3] = (bf16_t)((v.w - mu) * rs * gv.w + bv.w);
  *(bf16x4*)(outb + (size_t)row * D_DIM + threadIdx.x * 4) = o;
}

// ---------------------------------------------------------------------------
// Ortho loss from bf16 kphase: cos(kp_i)cos(kp_j)+sin..sin.. = cos(kp_i-kp_j)
// ---------------------------------------------------------------------------
__global__ __launch_bounds__(256) void ortho_partial(const bf16_t* __restrict__ kp,
                                                     const int* __restrict__ idx,
                                                     float* __restrict__ partial) {
  const int i = blockIdx.x;  // 0..31
  const int b = blockIdx.y;  // 0..3
  const int ri = idx[i];
  const bf16x4 ab = *(const bf16x4*)(kp + ((size_t)b * S_DIM + ri) * D_DIM + threadIdx.x * 4);
  float a0 = (float)ab[0], a1 = (float)ab[1], a2 = (float)ab[2], a3 = (float)ab[3];
  float sum = 0.f;
  for (int j = 0; j < 32; j++) {
    if (j == i) continue;
    const int rj = idx[j];
    const bf16x4 cb = *(const bf16x4*)(kp + ((size_t)b * S_DIM + rj) * D_DIM + threadIdx.x * 4);
    float d0 = cosf(a0 - (float)cb[0]);
    float d1 = cosf(a1 - (float)cb[1]);
    float d2 = cosf(a2 - (float)cb[2]);
    float d3 = cosf(a3 - (float)cb[3]);
    sum += d0 * d0 + d1 * d1 + d2 * d2 + d3 * d3;
  }
#pragma unroll
  for (int o = 32; o > 0; o >>= 1) sum += __shfl_down(sum, o);
  __shared__ float red[4];
  if ((threadIdx.x & 63) == 0) red[threadIdx.x >> 6] = sum;
  __syncthreads();
  if (threadIdx.x == 0) partial[b * 32 + i] = red[0] + red[1] + red[2] + red[3];
}

__global__ void ortho_final(const float* __restrict__ partial, float* __restrict__ outp) {
  if (threadIdx.x == 0) {
    double s = 0.0;
    for (int t = 0; t < 128; t++) s += (double)partial[t];
    const double denom = (double)(32 * 31) * 1024.0 + 1e-6;
    outp[0] = (float)(s / denom);
  }
}

// ---------------------------------------------------------------------------
// Orchestration. ws layout (MB offsets; peak 160 MB):
//   [  0,  6) QKVT bf16 [3072,1024] = [WvT | WkkpT | WqqpT]
//   [  6,  8) WoT            [  8, 12) WkpT||WqpT [2048,1024]
//   [ 12,  +) fused bias (3072 f32) + partial (128 f32)
//   [ 13, 17) Wk_b||Wq_b (dead after wfuse GEMM)
//   [ 32, 64) xb             -> ret_b after mega GEMM
//   [ 64, 96) value_b        -> lnb after scan
//   [ 96,128) kp_b           [128,160) qp_b
// ---------------------------------------------------------------------------
extern "C" void kernel_launch(void* const* d_in, const int* in_sizes, int n_in,
                              void* d_out, int out_size, void* d_ws, size_t ws_size,
                              hipStream_t stream) {
  const float* x = (const float*)d_in[0];
  const float* Wk = (const float*)d_in[1];
  const float* bk = (const float*)d_in[2];
  const float* Wv = (const float*)d_in[3];
  const float* bv = (const float*)d_in[4];
  const float* Wq = (const float*)d_in[5];
  const float* bq = (const float*)d_in[6];
  const float* Wkp = (const float*)d_in[7];
  const float* bkp = (const float*)d_in[8];
  const float* Wqp = (const float*)d_in[9];
  const float* bqp = (const float*)d_in[10];
  const float* ln_g = (const float*)d_in[11];
  const float* ln_b = (const float*)d_in[12];
  const float* Wo = (const float*)d_in[13];
  const float* bo = (const float*)d_in[14];
  const int* idx = (const int*)d_in[15];

  float* out = (float*)d_out;
  float* ortho_out = out + MD;

  char* ws = (char*)d_ws;
  const size_t MB = 1024 * 1024;
  bf16_t* QKVT = (bf16_t*)(ws + 0 * MB);     // [3072,1024]
  bf16_t* WoT = (bf16_t*)(ws + 6 * MB);
  bf16_t* WkpT2 = (bf16_t*)(ws + 8 * MB);    // [2048,1024]
  float* fbias = (float*)(ws + 12 * MB);     // 3072
  float* partial = (float*)(ws + 12 * MB + 16 * 1024);  // 128
  bf16_t* Wkqb = (bf16_t*)(ws + 13 * MB);    // Wk_b || Wq_b  [2][1024][1024]
  bf16_t* xb = (bf16_t*)(ws + 32 * MB);
  bf16_t* mega_out = (bf16_t*)(ws + 64 * MB);  // [3][16384][1024]
  bf16_t* kp_b = mega_out + MD;
  bf16_t* qp_b = mega_out + 2 * MD;
  bf16_t* ret_b = (bf16_t*)(ws + 32 * MB);   // reuses xb
  bf16_t* lnb = (bf16_t*)(ws + 64 * MB);     // reuses value_b

  // 0. prelude: transposes, casts, weight-fuse GEMM, fused bias
  prep_transpose<<<dim3(32, 32, 4), 256, 0, stream>>>(
      Wv, Wkp, Wqp, Wo, QKVT, WkpT2, WkpT2 + (size_t)D_DIM * D_DIM, WoT);
  prep_cast<<<18432, 256, 0, stream>>>(x, Wk, Wq, xb, Wkqb,
                                       Wkqb + (size_t)D_DIM * D_DIM);
  // WkkpT/WqqpT = (WkpT||WqpT) @ (Wk_b||Wq_b)^T  -> QKVT rows [1024,3072)
  gemm_mfma<3><<<128, 256, 0, stream>>>(WkpT2, Wkqb, nullptr, nullptr, nullptr,
                                        QKVT + (size_t)D_DIM * D_DIM);
  fused_bias_k<<<12, 256, 0, stream>>>(bv, bk, bkp, bq, bqp, Wkp, Wqp, fbias);

  // 1. mega GEMM: [value|kp|qp] = xb @ QKVT^T + fbias   (3072 blocks)
  gemm_mfma<0><<<24 * 128, 256, 0, stream>>>(xb, QKVT, fbias, nullptr, nullptr,
                                             mega_out);
  // 2. ortho from kp_b
  ortho_partial<<<dim3(32, B_DIM), 256, 0, stream>>>(kp_b, idx, partial);
  // 3. fused trig + chunk cumsum + retrieve -> ret_b (xb dead)
  phasor_scan<<<dim3(2, NC, B_DIM), 256, 0, stream>>>(mega_out, kp_b, qp_b, ret_b);
  // 4. LayerNorm -> lnb (value dead)
  layernorm_k<<<M_DIM, 256, 0, stream>>>(ret_b, ln_g, ln_b, lnb);
  // 5. out = x + lnb@Wo + bo
  gemm_mfma<2><<<8 * 128, 256, 0, stream>>>(lnb, WoT, bo, x, out, nullptr);
  // 6. ortho scalar
  ortho_final<<<1, 64, 0, stream>>>(partial, ortho_out);
}

// Round 5
// 484.538 us; speedup vs baseline: 5.3155x; 1.0246x over previous
//
#include <hip/hip_runtime.h>
#include <math.h>

#define D_DIM 1024
#define S_DIM 4096
#define B_DIM 4
#define CHUNK 64
#define NC (S_DIM / CHUNK)
#define M_DIM (B_DIM * S_DIM)   // 16384 rows
#define MD ((size_t)M_DIM * D_DIM)

typedef __bf16 bf16_t;
typedef __attribute__((ext_vector_type(8))) __bf16 bf16x8;
typedef __attribute__((ext_vector_type(4))) __bf16 bf16x4;
typedef __attribute__((ext_vector_type(2))) __bf16 bf16x2;
typedef __attribute__((ext_vector_type(4))) float f32x4;

// ---------------------------------------------------------------------------
// async 16B/lane global->LDS. LDS dest is wave-uniform base + lane*16.
// ---------------------------------------------------------------------------
__device__ __forceinline__ void async_copy16(const void* g, void* lds) {
  __builtin_amdgcn_global_load_lds(
      (const __attribute__((address_space(1))) unsigned int*)g,
      (__attribute__((address_space(3))) unsigned int*)lds, 16, 0, 0);
}

// ---------------------------------------------------------------------------
// bf16 MFMA GEMM, 128x128 tile, BK=64 as two 32-k sub-buffers (keeps the
// verified 64B-row LDS geometry for both global_load_lds staging and
// conflict-free ds_read_b128). Halves barrier-drain count vs BK=32: 16 iters,
// 32 MFMAs per drain. 4 waves 2x2, 16x16x32 MFMA 4x4/wave.
// MODE 0 (MEGA):  A=xb[16384,1024] @ QKVT[3072,1024]^T + fbias;
//                 out bf16 [t][16384][1024], t=bn>>10 (0=value,1=kp,2=qp)
// MODE 2 (FINAL): fp32 out Cf = A@Bt^T + bias + res
// MODE 3 (WFUSE): A=WkpT||WqpT [2048,1024]; tsel=bm>>10 selects Bt half
//                 and out half; out bf16 [2][1024][1024], no bias
// ---------------------------------------------------------------------------
template <int MODE>
__global__ __launch_bounds__(256) void gemm_mfma(const bf16_t* __restrict__ A,
                                                 const bf16_t* __restrict__ Bt,
                                                 const float* __restrict__ bias,
                                                 const float* __restrict__ res,
                                                 float* __restrict__ Cf,
                                                 bf16_t* __restrict__ Cb) {
  constexpr int K = D_DIM;
  constexpr int NB_N = (MODE == 0) ? 24 : 8;
  constexpr int NB_M = (MODE == 3) ? 16 : 128;
  __shared__ bf16_t sm[4 * 4096];   // As0 | As1 | Bs0 | Bs1, each 128x32

  const int bid = blockIdx.x;
  const int xcd = bid & 7;
  const int slot = bid >> 3;
  const int bm = (xcd * (NB_M / 8) + slot / NB_N) * 128;
  const int bn = (slot % NB_N) * 128;

  const int tid = threadIdx.x;
  const int lane = tid & 63;
  const int wave = tid >> 6;
  const int wm = wave & 1, wn = wave >> 1;
  const int quad = lane >> 4;
  const int l15 = lane & 15;

  bf16_t* As0 = sm;
  bf16_t* As1 = sm + 4096;
  bf16_t* Bs0 = sm + 8192;
  bf16_t* Bs1 = sm + 12288;

  const bf16_t* BtP = Bt;
  if (MODE == 3) BtP = Bt + (size_t)(bm >> 10) * D_DIM * D_DIM;

  f32x4 acc[4][4];
#pragma unroll
  for (int i = 0; i < 4; i++)
#pragma unroll
    for (int j = 0; j < 4; j++) acc[i][j] = (f32x4){0.f, 0.f, 0.f, 0.f};

  // staging: per 32-k sub-tile, 512 slots of 16B; slot e -> row e>>2, kgrp e&3
  const int e0 = tid, e1 = tid + 256;
  const int wofs = wave * 512;          // wave-uniform LDS elem offset (64 slots)
  const bf16_t* a0 = A + (size_t)(bm + (e0 >> 2)) * K + (e0 & 3) * 8;
  const bf16_t* a1 = A + (size_t)(bm + (e1 >> 2)) * K + (e1 & 3) * 8;
  const bf16_t* b0 = BtP + (size_t)(bn + (e0 >> 2)) * K + (e0 & 3) * 8;
  const bf16_t* b1 = BtP + (size_t)(bn + (e1 >> 2)) * K + (e1 & 3) * 8;

  for (int k0 = 0; k0 < K; k0 += 64) {
    // sub-k 0 (k0..k0+31) and sub-k 1 (k0+32..k0+63)
    async_copy16(a0 + k0, As0 + wofs);
    async_copy16(a1 + k0, As0 + 2048 + wofs);
    async_copy16(b0 + k0, Bs0 + wofs);
    async_copy16(b1 + k0, Bs0 + 2048 + wofs);
    async_copy16(a0 + k0 + 32, As1 + wofs);
    async_copy16(a1 + k0 + 32, As1 + 2048 + wofs);
    async_copy16(b0 + k0 + 32, Bs1 + wofs);
    async_copy16(b1 + k0 + 32, Bs1 + 2048 + wofs);
    __syncthreads();   // drains vmcnt: staged data visible

#pragma unroll
    for (int h = 0; h < 2; h++) {
      const bf16_t* Ah = h ? As1 : As0;
      const bf16_t* Bh = h ? Bs1 : Bs0;
      bf16x8 af[4], bfr[4];
#pragma unroll
      for (int t = 0; t < 4; t++) {
        af[t] = *(const bf16x8*)(Ah + (size_t)(wm * 64 + t * 16 + l15) * 32 + quad * 8);
        bfr[t] = *(const bf16x8*)(Bh + (size_t)(wn * 64 + t * 16 + l15) * 32 + quad * 8);
      }
#pragma unroll
      for (int mt = 0; mt < 4; mt++)
#pragma unroll
        for (int nt = 0; nt < 4; nt++)
          acc[mt][nt] =
              __builtin_amdgcn_mfma_f32_16x16x32_bf16(af[mt], bfr[nt], acc[mt][nt], 0, 0, 0);
    }
    __syncthreads();
  }

  // epilogue: C/D layout col=lane&15, row=quad*4+reg
  const int baserow = bm + wm * 64;
  const int basecol = bn + wn * 64 + l15;
#pragma unroll
  for (int mt = 0; mt < 4; mt++) {
#pragma unroll
    for (int nt = 0; nt < 4; nt++) {
      const int n = basecol + nt * 16;
      const float bv = (MODE == 3) ? 0.f : bias[n];
#pragma unroll
      for (int r = 0; r < 4; r++) {
        const int m = baserow + mt * 16 + quad * 4 + r;
        float v = acc[mt][nt][r] + bv;
        if (MODE == 2) {
          v += res[(size_t)m * D_DIM + n];
          Cf[(size_t)m * D_DIM + n] = v;
        } else if (MODE == 0) {
          Cb[(size_t)(bn >> 10) * MD + (size_t)m * D_DIM + (n & 1023)] = (bf16_t)v;
        } else {  // MODE 3
          Cb[(size_t)(bm >> 10) * D_DIM * D_DIM + (size_t)(m & 1023) * D_DIM + n] =
              (bf16_t)v;
        }
      }
    }
  }
}

// ---------------------------------------------------------------------------
// Prelude: z<4 -> weight transpose+cast (Wt[n][k] = (bf16)W[k][n]);
//          z>=4 -> flat fp32->bf16 cast of x | Wk | Wq.
// ---------------------------------------------------------------------------
__global__ __launch_bounds__(256) void prep_all(
    const float* __restrict__ s0, const float* __restrict__ s1,
    const float* __restrict__ s2, const float* __restrict__ s3,
    bf16_t* __restrict__ d0, bf16_t* __restrict__ d1,
    bf16_t* __restrict__ d2, bf16_t* __restrict__ d3,
    const float* __restrict__ x, const float* __restrict__ Wk,
    const float* __restrict__ Wq, bf16_t* __restrict__ xb,
    bf16_t* __restrict__ wkb, bf16_t* __restrict__ wqb) {
  const int z = blockIdx.z;
  if (z < 4) {
    const float* srcs[4] = {s0, s1, s2, s3};
    bf16_t* dsts[4] = {d0, d1, d2, d3};
    const float* W = srcs[z];
    bf16_t* Wt = dsts[z];
    __shared__ float tile[32][33];
    const int bx = blockIdx.x * 32;  // n
    const int by = blockIdx.y * 32;  // k
    const int tx = threadIdx.x & 31, ty = threadIdx.x >> 5;  // 32 x 8
#pragma unroll
    for (int r = 0; r < 32; r += 8)
      tile[ty + r][tx] = W[(size_t)(by + ty + r) * D_DIM + bx + tx];
    __syncthreads();
#pragma unroll
    for (int r = 0; r < 32; r += 8)
      Wt[(size_t)(bx + ty + r) * D_DIM + by + tx] = (bf16_t)tile[tx][ty + r];
  } else {
    // 18 z-slices x 1024 blocks x 256 thr = 4718592 float4 groups exactly
    size_t i = ((size_t)(z - 4) * 1024 + blockIdx.y * 32 + blockIdx.x) * 256 +
               threadIdx.x;
    const float* src;
    bf16_t* dst;
    size_t off;
    if (i < 4194304) { src = x; dst = xb; off = i; }
    else if (i < 4456448) { src = Wk; dst = wkb; off = i - 4194304; }
    else { src = Wq; dst = wqb; off = i - 4456448; }
    const float4 v = ((const float4*)src)[off];
    bf16x4 o;
    o[0] = (bf16_t)v.x; o[1] = (bf16_t)v.y; o[2] = (bf16_t)v.z; o[3] = (bf16_t)v.w;
    ((bf16x4*)dst)[off] = o;
  }
}

// ---------------------------------------------------------------------------
// Fused bias: fb[0:1024)=bv; fb[1024+c)=bk@Wkp[:,c]+bkp[c]; fb[2048+c) for q.
// ---------------------------------------------------------------------------
__global__ __launch_bounds__(256) void fused_bias_k(
    const float* __restrict__ bv, const float* __restrict__ bk,
    const float* __restrict__ bkp, const float* __restrict__ bq,
    const float* __restrict__ bqp, const float* __restrict__ Wkp,
    const float* __restrict__ Wqp, float* __restrict__ fb) {
  const int n = blockIdx.x * 256 + threadIdx.x;  // 0..3071
  const int t = n >> 10, c = n & 1023;
  if (t == 0) {
    fb[n] = bv[c];
    return;
  }
  const float* W = (t == 1) ? Wkp : Wqp;
  const float* b1 = (t == 1) ? bk : bq;
  const float* b2 = (t == 1) ? bkp : bqp;
  float s = b2[c];
#pragma unroll 8
  for (int k = 0; k < D_DIM; k++) s = fmaf(b1[k], W[(size_t)k * D_DIM + c], s);
  fb[n] = s;
}

// ---------------------------------------------------------------------------
// Fused phasor scan + LayerNorm. Block = (chunk, b), 512 threads, 64 KB LDS.
// Two 32-row passes: scan rows into LDS (cumsum state lives in registers
// across passes), then 8 waves LayerNorm 4 rows each, write bf16 lnb.
// Numerics identical to separate scan->bf16->LN (same rounding points).
// ---------------------------------------------------------------------------
__global__ __launch_bounds__(512) void scan_ln(const bf16_t* __restrict__ vb,
                                               const bf16_t* __restrict__ kp,
                                               const bf16_t* __restrict__ qp,
                                               const float* __restrict__ g,
                                               const float* __restrict__ bl,
                                               bf16_t* __restrict__ outb) {
  __shared__ bf16_t retl[32 * 1024];   // 64 KB
  const int chunk = blockIdx.x;
  const int b = blockIdx.y;
  const int tid = threadIdx.x;
  const int lane = tid & 63, wave = tid >> 6;
  const int c = tid * 2;
  const size_t base = ((size_t)(b * S_DIM + chunk * CHUNK)) * D_DIM + c;
  float2 mr = {0.f, 0.f}, mi = {0.f, 0.f};
  const float inv = 0.015625f;  // 1/sqrt(4096)

  for (int half = 0; half < 2; half++) {
    // -- scan 32 rows into LDS --
    for (int s8 = 0; s8 < 32; s8++) {
      const int s = half * 32 + s8;
      const size_t off = base + (size_t)s * D_DIM;
      bf16x2 v2 = *(const bf16x2*)(vb + off);
      bf16x2 k2 = *(const bf16x2*)(kp + off);
      bf16x2 q2 = *(const bf16x2*)(qp + off);
      float sk, ck, sq, cq;
      sincosf((float)k2[0], &sk, &ck);
      mr.x = fmaf((float)v2[0], ck, mr.x);
      mi.x = fmaf((float)v2[0], sk, mi.x);
      sincosf((float)k2[1], &sk, &ck);
      mr.y = fmaf((float)v2[1], ck, mr.y);
      mi.y = fmaf((float)v2[1], sk, mi.y);
      bf16x2 r;
      sincosf((float)q2[0], &sq, &cq);
      r[0] = (bf16_t)((mr.x * cq + mi.x * sq) * inv);
      sincosf((float)q2[1], &sq, &cq);
      r[1] = (bf16_t)((mr.y * cq + mi.y * sq) * inv);
      *(bf16x2*)(retl + s8 * 1024 + c) = r;
    }
    __syncthreads();
    // -- LayerNorm: wave handles rows wave*4 .. wave*4+3 --
#pragma unroll
    for (int j = 0; j < 4; j++) {
      const int r8 = wave * 4 + j;
      const int col0 = lane * 16;
      const bf16x8 va = *(const bf16x8*)(retl + r8 * 1024 + col0);
      const bf16x8 vb8 = *(const bf16x8*)(retl + r8 * 1024 + col0 + 8);
      float vf[16];
#pragma unroll
      for (int k = 0; k < 8; k++) { vf[k] = (float)va[k]; vf[8 + k] = (float)vb8[k]; }
      float s = 0.f, ss = 0.f;
#pragma unroll
      for (int k = 0; k < 16; k++) { s += vf[k]; ss += vf[k] * vf[k]; }
#pragma unroll
      for (int o = 32; o > 0; o >>= 1) {
        s += __shfl_down(s, o);
        ss += __shfl_down(ss, o);
      }
      s = __shfl(s, 0);
      ss = __shfl(ss, 0);
      const float mu = s * (1.f / D_DIM);
      const float var = ss * (1.f / D_DIM) - mu * mu;
      const float rs = 1.f / sqrtf(var + 1e-5f);
      const int m = b * S_DIM + chunk * CHUNK + half * 32 + r8;
      bf16x8 o1, o2;
#pragma unroll
      for (int q = 0; q < 4; q++) {
        const float4 gv = *(const float4*)(g + col0 + 4 * q);
        const float4 bv = *(const float4*)(bl + col0 + 4 * q);
        const int kbase = 4 * q;
        float r0 = (vf[kbase + 0] - mu) * rs * gv.x + bv.x;
        float r1 = (vf[kbase + 1] - mu) * rs * gv.y + bv.y;
        float r2 = (vf[kbase + 2] - mu) * rs * gv.z + bv.z;
        float r3 = (vf[kbase + 3] - mu) * rs * gv.w + bv.w;
        if (q < 2) {
          o1[kbase + 0] = (bf16_t)r0; o1[kbase + 1] = (bf16_t)r1;
          o1[kbase + 2] = (bf16_t)r2; o1[kbase + 3] = (bf16_t)r3;
        } else {
          o2[kbase - 8] = (bf16_t)r0; o2[kbase - 7] = (bf16_t)r1;
          o2[kbase - 6] = (bf16_t)r2; o2[kbase - 5] = (bf16_t)r3;
        }
      }
      *(bf16x8*)(outb + (size_t)m * D_DIM + col0) = o1;
      *(bf16x8*)(outb + (size_t)m * D_DIM + col0 + 8) = o2;
    }
    __syncthreads();
  }
}

// ---------------------------------------------------------------------------
// Ortho loss from bf16 kphase: cos(kp_i)cos(kp_j)+sin..sin.. = cos(kp_i-kp_j)
// ---------------------------------------------------------------------------
__global__ __launch_bounds__(256) void ortho_partial(const bf16_t* __restrict__ kp,
                                                     const int* __restrict__ idx,
                                                     float* __restrict__ partial) {
  const int i = blockIdx.x;  // 0..31
  const int b = blockIdx.y;  // 0..3
  const int ri = idx[i];
  const bf16x4 ab = *(const bf16x4*)(kp + ((size_t)b * S_DIM + ri) * D_DIM + threadIdx.x * 4);
  float a0 = (float)ab[0], a1 = (float)ab[1], a2 = (float)ab[2], a3 = (float)ab[3];
  float sum = 0.f;
  for (int j = 0; j < 32; j++) {
    if (j == i) continue;
    const int rj = idx[j];
    const bf16x4 cb = *(const bf16x4*)(kp + ((size_t)b * S_DIM + rj) * D_DIM + threadIdx.x * 4);
    float d0 = cosf(a0 - (float)cb[0]);
    float d1 = cosf(a1 - (float)cb[1]);
    float d2 = cosf(a2 - (float)cb[2]);
    float d3 = cosf(a3 - (float)cb[3]);
    sum += d0 * d0 + d1 * d1 + d2 * d2 + d3 * d3;
  }
#pragma unroll
  for (int o = 32; o > 0; o >>= 1) sum += __shfl_down(sum, o);
  __shared__ float red[4];
  if ((threadIdx.x & 63) == 0) red[threadIdx.x >> 6] = sum;
  __syncthreads();
  if (threadIdx.x == 0) partial[b * 32 + i] = red[0] + red[1] + red[2] + red[3];
}

__global__ void ortho_final(const float* __restrict__ partial, float* __restrict__ outp) {
  if (threadIdx.x == 0) {
    double s = 0.0;
    for (int t = 0; t < 128; t++) s += (double)partial[t];
    const double denom = (double)(32 * 31) * 1024.0 + 1e-6;
    outp[0] = (float)(s / denom);
  }
}

// ---------------------------------------------------------------------------
// Orchestration. ws layout (MB offsets; peak 160 MB):
//   [  0,  6) QKVT bf16 [3072,1024] = [WvT | WkkpT | WqqpT]
//   [  6,  8) WoT            [  8, 12) WkpT||WqpT [2048,1024]
//   [ 12,  +) fused bias (3072 f32) + partial (128 f32)
//   [ 13, 17) Wk_b||Wq_b (dead after wfuse GEMM)
//   [ 32, 64) xb             -> lnb after mega GEMM
//   [ 64, 96) value_b        [ 96,128) kp_b        [128,160) qp_b
// ---------------------------------------------------------------------------
extern "C" void kernel_launch(void* const* d_in, const int* in_sizes, int n_in,
                              void* d_out, int out_size, void* d_ws, size_t ws_size,
                              hipStream_t stream) {
  const float* x = (const float*)d_in[0];
  const float* Wk = (const float*)d_in[1];
  const float* bk = (const float*)d_in[2];
  const float* Wv = (const float*)d_in[3];
  const float* bv = (const float*)d_in[4];
  const float* Wq = (const float*)d_in[5];
  const float* bq = (const float*)d_in[6];
  const float* Wkp = (const float*)d_in[7];
  const float* bkp = (const float*)d_in[8];
  const float* Wqp = (const float*)d_in[9];
  const float* bqp = (const float*)d_in[10];
  const float* ln_g = (const float*)d_in[11];
  const float* ln_b = (const float*)d_in[12];
  const float* Wo = (const float*)d_in[13];
  const float* bo = (const float*)d_in[14];
  const int* idx = (const int*)d_in[15];

  float* out = (float*)d_out;
  float* ortho_out = out + MD;

  char* ws = (char*)d_ws;
  const size_t MB = 1024 * 1024;
  bf16_t* QKVT = (bf16_t*)(ws + 0 * MB);     // [3072,1024]
  bf16_t* WoT = (bf16_t*)(ws + 6 * MB);
  bf16_t* WkpT2 = (bf16_t*)(ws + 8 * MB);    // [2048,1024]
  float* fbias = (float*)(ws + 12 * MB);     // 3072
  float* partial = (float*)(ws + 12 * MB + 16 * 1024);  // 128
  bf16_t* Wkqb = (bf16_t*)(ws + 13 * MB);    // Wk_b || Wq_b  [2][1024][1024]
  bf16_t* xb = (bf16_t*)(ws + 32 * MB);
  bf16_t* mega_out = (bf16_t*)(ws + 64 * MB);  // [3][16384][1024]
  bf16_t* kp_b = mega_out + MD;
  bf16_t* qp_b = mega_out + 2 * MD;
  bf16_t* lnb = (bf16_t*)(ws + 32 * MB);     // reuses xb (dead after mega)

  // 0. prelude: transposes + casts (one dispatch), wfuse GEMM, fused bias
  prep_all<<<dim3(32, 32, 22), 256, 0, stream>>>(
      Wv, Wkp, Wqp, Wo, QKVT, WkpT2, WkpT2 + (size_t)D_DIM * D_DIM, WoT,
      x, Wk, Wq, xb, Wkqb, Wkqb + (size_t)D_DIM * D_DIM);
  // WkkpT/WqqpT = (WkpT||WqpT) @ (Wk_b||Wq_b)^T  -> QKVT rows [1024,3072)
  gemm_mfma<3><<<128, 256, 0, stream>>>(WkpT2, Wkqb, nullptr, nullptr, nullptr,
                                        QKVT + (size_t)D_DIM * D_DIM);
  fused_bias_k<<<12, 256, 0, stream>>>(bv, bk, bkp, bq, bqp, Wkp, Wqp, fbias);

  // 1. mega GEMM: [value|kp|qp] = xb @ QKVT^T + fbias   (3072 blocks)
  gemm_mfma<0><<<24 * 128, 256, 0, stream>>>(xb, QKVT, fbias, nullptr, nullptr,
                                             mega_out);
  // 2. ortho from kp_b
  ortho_partial<<<dim3(32, B_DIM), 256, 0, stream>>>(kp_b, idx, partial);
  // 3. fused trig + chunk cumsum + retrieve + LayerNorm -> lnb (xb dead)
  scan_ln<<<dim3(NC, B_DIM), 512, 0, stream>>>(mega_out, kp_b, qp_b, ln_g, ln_b,
                                               lnb);
  // 4. out = x + lnb@Wo + bo
  gemm_mfma<2><<<8 * 128, 256, 0, stream>>>(lnb, WoT, bo, x, out, nullptr);
  // 5. ortho scalar
  ortho_final<<<1, 64, 0, stream>>>(partial, ortho_out);
}